// Round 3
// baseline (247.250 us; speedup 1.0000x reference)
//
#include <hip/hip_runtime.h>
#include <math.h>

#define N_TOK 16384
#define D_DIM 512
#define PI_F 3.14159265358979323846f

typedef __bf16 bf16x8 __attribute__((ext_vector_type(8)));
typedef __bf16 bf16x4 __attribute__((ext_vector_type(4)));
typedef float floatx4 __attribute__((ext_vector_type(4)));

// ---------------------------------------------------------------------------
// Kernel A: precompute per-(char, d) tables + convert W to bf16.
//  blocks 0..95   : table[c][d] = {M1re, M1im, M2re, M2im}
//                   M1 = w1(d)*mod1(c,d)*filt(d); M2 = w2(d)*mod2(c,d)*filt(d)
//  blocks 96..351 : W fp32 -> bf16
// ---------------------------------------------------------------------------
__global__ __launch_bounds__(256) void setup_kernel(
    const float* __restrict__ W, float4* __restrict__ table,
    __bf16* __restrict__ Wb) {
  const int bid = blockIdx.x;
  const int tid = threadIdx.x;
  if (bid < 96) {
    const float lam = (float)bid / 96.0f;
#pragma unroll
    for (int q = 0; q < 2; ++q) {
      const int d = tid + q * 256;
      const float fi = (float)d;
      float s1, c1, s2, c2;
      sincosf((2.0f * PI_F / 512.0f) * fi * lam, &s1, &c1);          // mod1
      sincosf((4.0f * PI_F / 512.0f) * 1.7f * fi * lam, &s2, &c2);   // mod2
      const float w1 = 0.6f + 0.4f * sinf(0.1f * fi);
      const float w2 = 0.4f + 0.6f * cosf(0.15f * fi);
      const float kv = fi + 1.0f;
      float fs1, fc1, fs2, fc2;
      sincosf(1.5f * atanf(logf(kv + 1e-10f)), &fs1, &fc1);
      sincosf(0.8f * sinf(0.1f * kv), &fs2, &fc2);
      const float fre = 0.7f * fc1 + 0.3f * fc2;
      const float fim = 0.7f * fs1 + 0.3f * fs2;
      table[bid * 512 + d] = make_float4(
          w1 * (c1 * fre - s1 * fim), w1 * (c1 * fim + s1 * fre),
          w2 * (c2 * fre - s2 * fim), w2 * (c2 * fim + s2 * fre));
    }
  } else {
    const int i = (bid - 96) * 256 + tid;
    const float4 w = ((const float4*)W)[i];
    bf16x4 o;
    o[0] = (__bf16)w.x; o[1] = (__bf16)w.y; o[2] = (__bf16)w.z; o[3] = (__bf16)w.w;
    ((bf16x4*)Wb)[i] = o;
  }
}

// ---------------------------------------------------------------------------
// Kernel B: FUSED wave -> GEMM -> LayerNorm -> quaternion epilogue.
// Block = 32 rows x 512 cols, 256 threads (4 waves, each wave owns a 128-col
// strip of all 32 rows). A (bf16, MFMA fragment order) lives in LDS; B frags
// are read per-wave straight from L2-resident Wb -> no barriers in K-loop.
// ---------------------------------------------------------------------------
__global__ __launch_bounds__(256) void fused_kernel(
    const int* __restrict__ char_idx, const int* __restrict__ pos,
    const float4* __restrict__ table, const __bf16* __restrict__ Wb,
    const float* __restrict__ b, const float* __restrict__ gamma,
    const float* __restrict__ beta_ln, const float* __restrict__ noise,
    const float* __restrict__ sem, float4* __restrict__ out) {
  // A in fragment order: elem((kc,mt), lane, j) at ((kc*2+mt)*64 + lane)*8 + j
  __shared__ __align__(16) __bf16 A_lds[16 * 2 * 64 * 8];   // 32 KB
  __shared__ float2 rc1[32], rc2[32], rc3[32];              // quaternion consts
  __shared__ float part[4][32][2];                          // per-wave LN partials
  __shared__ float stats[32][2];                            // mu, rstd

  const int tid = threadIdx.x;
  const int lane = tid & 63, w = tid >> 6;
  const int row0 = blockIdx.x * 32;
  const float ct = 0.99500416527f, st = 0.09983341664f;     // cos/sin(0.1)

  // ---- Phase 1: wave state for rows w*8 .. w*8+7, write A to LDS ----
  for (int rr = 0; rr < 8; ++rr) {
    const int m = w * 8 + rr;
    const int n = row0 + m;
    const int c = char_idx[n];
    const float lam = (float)c * (1.0f / 96.0f);
    const float t = (float)pos[n] * 0.01f;
    const float omega = 2.0f * PI_F * 1.5f;
    const float kwav = 2.0f * PI_F / 1.7f;
    const float lam2 = lam * lam;
    float sp1, cp1, sp2, cp2;
    __sincosf(omega * t - kwav * lam + 0.8f * lam2, &sp1, &cp1);
    __sincosf(omega * t * 1.5f - kwav * lam * 0.7f + 1.04f * lam2, &sp2, &cp2);
    const float a1 = __sinf(omega * t + 1.5f * lam);
    const float a2 = __cosf(omega * t * 0.8f + 1.8f * lam);
    const float w1re = a1 * cp1, w1im = a1 * sp1;
    const float w2re = a2 * cp2, w2im = a2 * sp2;

    // lane handles k = lane*8 + j (8 contiguous table float4s)
    const float4* tp = table + c * 512 + lane * 8;
    float zre[8], zim[8], ss = 0.0f;
#pragma unroll
    for (int j = 0; j < 8; ++j) {
      const float4 mm = tp[j];
      zre[j] = w1re * mm.x - w1im * mm.y + w2re * mm.z - w2im * mm.w;
      zim[j] = w1re * mm.y + w1im * mm.x + w2re * mm.w + w2im * mm.z;
      ss += zre[j] * zre[j] + zim[j] * zim[j];
    }
#pragma unroll
    for (int off = 32; off > 0; off >>= 1) ss += __shfl_down(ss, off, 64);
    ss = __shfl(ss, 0, 64);
    const float inv = 1.0f / (sqrtf(ss) + 1e-8f);
    bf16x8 av;
#pragma unroll
    for (int j = 0; j < 8; ++j) av[j] = (__bf16)((zre[j] * ct - zim[j] * st) * inv);
    // k = lane*8+j -> kc = lane>>2, part = lane&3, jj = j
    const int kc = lane >> 2, prt = lane & 3, mt = m >> 4;
    *(bf16x8*)(A_lds + (((kc * 2 + mt) * 64) + ((prt << 4) | (m & 15))) * 8) = av;

    if (lane == 0) {   // per-row quaternion angle-addition constants
      const float cpm = (float)c * 0.01f;
      float s, cc;
      __sincosf(cpm, &s, &cc);
      rc1[m] = make_float2(sem[c * 4 + 0] * cc, sem[c * 4 + 0] * s);
      __sincosf(cpm * 1.3f, &s, &cc);
      rc2[m] = make_float2(sem[c * 4 + 1] * cc, sem[c * 4 + 1] * s);
      __sincosf(cpm * 0.7f, &s, &cc);
      rc3[m] = make_float2(sem[c * 4 + 2] * cc, sem[c * 4 + 2] * s);
    }
  }
  __syncthreads();

  // ---- Phase 2: K-loop, barrier-free. Wave w owns cols [w*128, w*128+128) ----
  const int cl = lane & 15, kq = lane >> 4;
  const int wn = w * 128;
  const __bf16* Bbase = Wb + (size_t)(wn + cl) * 512 + kq * 8;
  floatx4 acc[2][8] = {};
  bf16x8 bcur[8], bnxt[8];
#pragma unroll
  for (int j = 0; j < 8; ++j) bcur[j] = *(const bf16x8*)(Bbase + j * 16 * 512);
  for (int kc = 0; kc < 16; ++kc) {
    if (kc < 15) {
#pragma unroll
      for (int j = 0; j < 8; ++j)
        bnxt[j] = *(const bf16x8*)(Bbase + j * 16 * 512 + (kc + 1) * 32);
    }
    const bf16x8 a0 = *(const bf16x8*)(A_lds + ((kc * 2 + 0) * 64 + lane) * 8);
    const bf16x8 a1 = *(const bf16x8*)(A_lds + ((kc * 2 + 1) * 64 + lane) * 8);
#pragma unroll
    for (int j = 0; j < 8; ++j) {
      acc[0][j] = __builtin_amdgcn_mfma_f32_16x16x32_bf16(a0, bcur[j], acc[0][j], 0, 0, 0);
      acc[1][j] = __builtin_amdgcn_mfma_f32_16x16x32_bf16(a1, bcur[j], acc[1][j], 0, 0, 0);
    }
#pragma unroll
    for (int j = 0; j < 8; ++j) bcur[j] = bnxt[j];
  }

  // ---- Phase 3: bias + LayerNorm partials ----
  float bj[8], gj[8], btj[8], cph[8], sph[8];
#pragma unroll
  for (int j = 0; j < 8; ++j) {
    const int col = wn + j * 16 + cl;
    bj[j] = b[col]; gj[j] = gamma[col]; btj[j] = beta_ln[col];
    __sincosf((2.0f * PI_F / 512.0f) * (float)col, &sph[j], &cph[j]);
  }
  float ps[8] = {}, ps2[8] = {};
#pragma unroll
  for (int i = 0; i < 2; ++i)
#pragma unroll
    for (int j = 0; j < 8; ++j)
#pragma unroll
      for (int r = 0; r < 4; ++r) {
        const float v = acc[i][j][r] + bj[j];
        acc[i][j][r] = v;
        ps[i * 4 + r] += v;
        ps2[i * 4 + r] += v * v;
      }
  // reduce over the 16 lanes (same rows, different cols)
#pragma unroll
  for (int mask = 1; mask < 16; mask <<= 1)
#pragma unroll
    for (int tt = 0; tt < 8; ++tt) {
      ps[tt] += __shfl_xor(ps[tt], mask, 64);
      ps2[tt] += __shfl_xor(ps2[tt], mask, 64);
    }
  if (cl == 0) {
#pragma unroll
    for (int i = 0; i < 2; ++i)
#pragma unroll
      for (int r = 0; r < 4; ++r) {
        const int m = i * 16 + kq * 4 + r;
        part[w][m][0] = ps[i * 4 + r];
        part[w][m][1] = ps2[i * 4 + r];
      }
  }
  __syncthreads();
  if (tid < 32) {
    const float s = part[0][tid][0] + part[1][tid][0] + part[2][tid][0] + part[3][tid][0];
    const float s2 = part[0][tid][1] + part[1][tid][1] + part[2][tid][1] + part[3][tid][1];
    const float mu = s * (1.0f / 512.0f);
    const float var = s2 * (1.0f / 512.0f) - mu * mu;
    stats[tid][0] = mu;
    stats[tid][1] = rsqrtf(var + 1e-5f);
  }
  __syncthreads();

  // ---- Phase 4: normalize + noise + quaternion, float4 stores ----
#pragma unroll
  for (int i = 0; i < 2; ++i)
#pragma unroll
    for (int r = 0; r < 4; ++r) {
      const int m = i * 16 + kq * 4 + r;
      const float mu = stats[m][0], rstd = stats[m][1];
      const float2 c1 = rc1[m], c2 = rc2[m], c3 = rc3[m];
      const size_t rowoff = (size_t)(row0 + m) * 512;
#pragma unroll
      for (int j = 0; j < 8; ++j) {
        const int col = wn + j * 16 + cl;
        const float y = (acc[i][j][r] - mu) * rstd * gj[j] + btj[j]
                        + 0.01f * noise[rowoff + col];
        const float c2p = cph[j] * cph[j] - sph[j] * sph[j];   // cos(2ph)
        const float s2p = 2.0f * sph[j] * cph[j];              // sin(2ph)
        const float q1 = y * (c1.x * cph[j] - c1.y * sph[j]);  // sw0*cos(ph+cpm)
        const float q2 = y * (c2.x * sph[j] + c2.y * cph[j]);  // sw1*sin(ph+1.3cpm)
        const float q3 = y * (c3.x * c2p - c3.y * s2p);        // sw2*cos(2ph+0.7cpm)
        out[rowoff + col] = make_float4(y, q1, q2, q3);
      }
    }
}

extern "C" void kernel_launch(void* const* d_in, const int* in_sizes, int n_in,
                              void* d_out, int out_size, void* d_ws, size_t ws_size,
                              hipStream_t stream) {
  const int* char_idx = (const int*)d_in[0];
  const int* pos      = (const int*)d_in[1];
  const float* W      = (const float*)d_in[2];
  const float* b      = (const float*)d_in[3];
  const float* gamma  = (const float*)d_in[4];
  const float* beta_ln= (const float*)d_in[5];
  const float* noise  = (const float*)d_in[6];
  const float* sem    = (const float*)d_in[7];

  float4* table = (float4*)d_ws;                 // 96*512*16B = 768 KB
  __bf16* Wb    = (__bf16*)(table + 96 * 512);   // 512*512*2B = 512 KB

  setup_kernel<<<352, 256, 0, stream>>>(W, table, Wb);
  fused_kernel<<<N_TOK / 32, 256, 0, stream>>>(char_idx, pos, table, Wb, b,
                                               gamma, beta_ln, noise, sem,
                                               (float4*)d_out);
}

// Round 4
// 206.396 us; speedup vs baseline: 1.1979x; 1.1979x over previous
//
#include <hip/hip_runtime.h>
#include <math.h>

#define N_TOK 16384
#define PI_F 3.14159265358979323846f

typedef __bf16 bf16x8 __attribute__((ext_vector_type(8)));
typedef float floatx4 __attribute__((ext_vector_type(4)));

// ---------------------------------------------------------------------------
// Kernel A: precompute tables.
//  blocks 0..95   : table[c][d] = {M1re,M1im,M2re,M2im}
//  blocks 96..223 : pack W (fp32 row-major [col][k]) into bf16 MFMA-fragment
//                   order: Bf[((ct*16+kc)*64 + lane)*8 + j] = W[ct*16+(lane&15)]
//                   [kc*32+(lane>>4)*8+j]  -> every B-frag load is 1KB contig.
// ---------------------------------------------------------------------------
__global__ __launch_bounds__(256) void setup_kernel(
    const float* __restrict__ W, float4* __restrict__ table,
    __bf16* __restrict__ Bf) {
  const int bid = blockIdx.x;
  const int tid = threadIdx.x;
  if (bid < 96) {
    const float lam = (float)bid / 96.0f;
#pragma unroll
    for (int q = 0; q < 2; ++q) {
      const int d = tid + q * 256;
      const float fi = (float)d;
      float s1, c1, s2, c2;
      sincosf((2.0f * PI_F / 512.0f) * fi * lam, &s1, &c1);          // mod1
      sincosf((4.0f * PI_F / 512.0f) * 1.7f * fi * lam, &s2, &c2);   // mod2
      const float w1 = 0.6f + 0.4f * sinf(0.1f * fi);
      const float w2 = 0.4f + 0.6f * cosf(0.15f * fi);
      const float kv = fi + 1.0f;
      float fs1, fc1, fs2, fc2;
      sincosf(1.5f * atanf(logf(kv + 1e-10f)), &fs1, &fc1);
      sincosf(0.8f * sinf(0.1f * kv), &fs2, &fc2);
      const float fre = 0.7f * fc1 + 0.3f * fc2;
      const float fim = 0.7f * fs1 + 0.3f * fs2;
      table[bid * 512 + d] = make_float4(
          w1 * (c1 * fre - s1 * fim), w1 * (c1 * fim + s1 * fre),
          w2 * (c2 * fre - s2 * fim), w2 * (c2 * fim + s2 * fre));
    }
  } else {
    const int i = (bid - 96) * 256 + tid;   // 0..32767 == (ct*16+kc)*64+lane
    const int ct = i >> 10;
    const int kc = (i >> 6) & 15;
    const int lane = i & 63;
    const int cl = lane & 15, kq = lane >> 4;
    const float* src = W + (size_t)(ct * 16 + cl) * 512 + kc * 32 + kq * 8;
    bf16x8 o;
#pragma unroll
    for (int j = 0; j < 8; ++j) o[j] = (__bf16)src[j];
    *(bf16x8*)(Bf + (size_t)i * 8) = o;
  }
}

// ---------------------------------------------------------------------------
// Kernel B: FUSED wave -> GEMM -> LayerNorm -> quaternion epilogue.
// 512 threads = 8 waves; block = 32 rows x 512 cols; wave w owns 64-col strip.
// A (bf16 fragment order) in LDS; B frags streamed from L2-resident Bf via
// fully-coalesced 1KB loads with ping-pong prefetch. Barrier-free K-loop.
// ---------------------------------------------------------------------------
__global__ __launch_bounds__(512, 4) void fused_kernel(
    const int* __restrict__ char_idx, const int* __restrict__ pos,
    const float4* __restrict__ table, const __bf16* __restrict__ Bf,
    const float* __restrict__ b, const float* __restrict__ gamma,
    const float* __restrict__ beta_ln, const float* __restrict__ noise,
    const float* __restrict__ sem, float4* __restrict__ out) {
  // A frag elem((kc,mt), lane, j) at ((kc*2+mt)*64 + lane)*8 + j
  __shared__ __align__(16) __bf16 A_lds[16 * 2 * 64 * 8];   // 32 KB
  __shared__ float2 rc1[32], rc2[32], rc3[32];
  __shared__ float part[8][32][2];
  __shared__ float stats[32][2];

  const int tid = threadIdx.x;
  const int lane = tid & 63, w = tid >> 6;
  const int row0 = blockIdx.x * 32;
  const float ctR = 0.99500416527f, stR = 0.09983341664f;   // cos/sin(0.1)

  // ---- Phase 1: wave state for rows w*4 .. w*4+3 -> A_lds ----
  for (int rr = 0; rr < 4; ++rr) {
    const int m = w * 4 + rr;
    const int n = row0 + m;
    const int c = char_idx[n];
    const float lam = (float)c * (1.0f / 96.0f);
    const float t = (float)pos[n] * 0.01f;
    const float omega = 2.0f * PI_F * 1.5f;
    const float kwav = 2.0f * PI_F / 1.7f;
    const float lam2 = lam * lam;
    float sp1, cp1, sp2, cp2;
    __sincosf(omega * t - kwav * lam + 0.8f * lam2, &sp1, &cp1);
    __sincosf(omega * t * 1.5f - kwav * lam * 0.7f + 1.04f * lam2, &sp2, &cp2);
    const float a1 = __sinf(omega * t + 1.5f * lam);
    const float a2 = __cosf(omega * t * 0.8f + 1.8f * lam);
    const float w1re = a1 * cp1, w1im = a1 * sp1;
    const float w2re = a2 * cp2, w2im = a2 * sp2;

    const float4* tp = table + c * 512 + lane * 8;   // k = lane*8 + j
    float zre[8], zim[8], ss = 0.0f;
#pragma unroll
    for (int j = 0; j < 8; ++j) {
      const float4 mm = tp[j];
      zre[j] = w1re * mm.x - w1im * mm.y + w2re * mm.z - w2im * mm.w;
      zim[j] = w1re * mm.y + w1im * mm.x + w2re * mm.w + w2im * mm.z;
      ss += zre[j] * zre[j] + zim[j] * zim[j];
    }
#pragma unroll
    for (int off = 32; off > 0; off >>= 1) ss += __shfl_xor(ss, off, 64);
    const float inv = 1.0f / (sqrtf(ss) + 1e-8f);
    bf16x8 av;
#pragma unroll
    for (int j = 0; j < 8; ++j) av[j] = (__bf16)((zre[j] * ctR - zim[j] * stR) * inv);
    const int kc = lane >> 2, prt = lane & 3, mt = m >> 4;
    *(bf16x8*)(A_lds + (((kc * 2 + mt) * 64) + ((prt << 4) | (m & 15))) * 8) = av;

    if (lane == 0) {
      const float cpm = (float)c * 0.01f;
      float s, cc;
      __sincosf(cpm, &s, &cc);
      rc1[m] = make_float2(sem[c * 4 + 0] * cc, sem[c * 4 + 0] * s);
      __sincosf(cpm * 1.3f, &s, &cc);
      rc2[m] = make_float2(sem[c * 4 + 1] * cc, sem[c * 4 + 1] * s);
      __sincosf(cpm * 0.7f, &s, &cc);
      rc3[m] = make_float2(sem[c * 4 + 2] * cc, sem[c * 4 + 2] * s);
    }
  }
  __syncthreads();

  // ---- Phase 2: barrier-free K-loop; wave w -> col-tiles w*4 .. w*4+3 ----
  const int cl = lane & 15, kq = lane >> 4;
  const __bf16* Bp = Bf + ((size_t)(w * 4) * 16 + 0) * 64 * 8 + lane * 8;
  // frag (j, kc) at Bp + (j*16 + kc)*512 elements
  floatx4 acc[2][4] = {};
  bf16x8 bcur[4], bnxt[4];
  bf16x8 a0 = *(const bf16x8*)(A_lds + lane * 8);
  bf16x8 a1 = *(const bf16x8*)(A_lds + (64 + lane) * 8);
  bf16x8 a0n, a1n;
#pragma unroll
  for (int j = 0; j < 4; ++j) bcur[j] = *(const bf16x8*)(Bp + (size_t)(j * 16) * 512);
  for (int kc = 0; kc < 16; ++kc) {
    if (kc < 15) {
#pragma unroll
      for (int j = 0; j < 4; ++j)
        bnxt[j] = *(const bf16x8*)(Bp + (size_t)(j * 16 + kc + 1) * 512);
      a0n = *(const bf16x8*)(A_lds + (((kc + 1) * 2 + 0) * 64 + lane) * 8);
      a1n = *(const bf16x8*)(A_lds + (((kc + 1) * 2 + 1) * 64 + lane) * 8);
    }
#pragma unroll
    for (int j = 0; j < 4; ++j) {
      acc[0][j] = __builtin_amdgcn_mfma_f32_16x16x32_bf16(a0, bcur[j], acc[0][j], 0, 0, 0);
      acc[1][j] = __builtin_amdgcn_mfma_f32_16x16x32_bf16(a1, bcur[j], acc[1][j], 0, 0, 0);
    }
    a0 = a0n; a1 = a1n;
#pragma unroll
    for (int j = 0; j < 4; ++j) bcur[j] = bnxt[j];
  }

  // ---- Phase 3: bias + LayerNorm partials ----
  float bj[4], gj[4], btj[4], cph[4], sph[4];
#pragma unroll
  for (int j = 0; j < 4; ++j) {
    const int col = w * 64 + j * 16 + cl;
    bj[j] = b[col]; gj[j] = gamma[col]; btj[j] = beta_ln[col];
    __sincosf((2.0f * PI_F / 512.0f) * (float)col, &sph[j], &cph[j]);
  }
  float ps[8] = {}, ps2[8] = {};
#pragma unroll
  for (int i = 0; i < 2; ++i)
#pragma unroll
    for (int j = 0; j < 4; ++j)
#pragma unroll
      for (int r = 0; r < 4; ++r) {
        const float v = acc[i][j][r] + bj[j];
        acc[i][j][r] = v;
        ps[i * 4 + r] += v;
        ps2[i * 4 + r] += v * v;
      }
#pragma unroll
  for (int mask = 1; mask < 16; mask <<= 1)
#pragma unroll
    for (int tt = 0; tt < 8; ++tt) {
      ps[tt] += __shfl_xor(ps[tt], mask, 64);
      ps2[tt] += __shfl_xor(ps2[tt], mask, 64);
    }
  if (cl == 0) {
#pragma unroll
    for (int i = 0; i < 2; ++i)
#pragma unroll
      for (int r = 0; r < 4; ++r) {
        const int m = i * 16 + kq * 4 + r;
        part[w][m][0] = ps[i * 4 + r];
        part[w][m][1] = ps2[i * 4 + r];
      }
  }
  __syncthreads();
  if (tid < 32) {
    float s = 0.0f, s2 = 0.0f;
#pragma unroll
    for (int ww = 0; ww < 8; ++ww) { s += part[ww][tid][0]; s2 += part[ww][tid][1]; }
    const float mu = s * (1.0f / 512.0f);
    const float var = s2 * (1.0f / 512.0f) - mu * mu;
    stats[tid][0] = mu;
    stats[tid][1] = rsqrtf(var + 1e-5f);
  }
  __syncthreads();

  // ---- Phase 4: normalize + noise + quaternion, float4 stores ----
#pragma unroll
  for (int i = 0; i < 2; ++i)
#pragma unroll
    for (int r = 0; r < 4; ++r) {
      const int m = i * 16 + kq * 4 + r;
      const float mu = stats[m][0], rstd = stats[m][1];
      const float2 c1 = rc1[m], c2 = rc2[m], c3 = rc3[m];
      const size_t rowoff = (size_t)(row0 + m) * 512;
#pragma unroll
      for (int j = 0; j < 4; ++j) {
        const int col = w * 64 + j * 16 + cl;
        const float y = (acc[i][j][r] - mu) * rstd * gj[j] + btj[j]
                        + 0.01f * noise[rowoff + col];
        const float c2p = cph[j] * cph[j] - sph[j] * sph[j];   // cos(2ph)
        const float s2p = 2.0f * sph[j] * cph[j];              // sin(2ph)
        const float q1 = y * (c1.x * cph[j] - c1.y * sph[j]);
        const float q2 = y * (c2.x * sph[j] + c2.y * cph[j]);
        const float q3 = y * (c3.x * c2p - c3.y * s2p);
        out[rowoff + col] = make_float4(y, q1, q2, q3);
      }
    }
}

extern "C" void kernel_launch(void* const* d_in, const int* in_sizes, int n_in,
                              void* d_out, int out_size, void* d_ws, size_t ws_size,
                              hipStream_t stream) {
  const int* char_idx = (const int*)d_in[0];
  const int* pos      = (const int*)d_in[1];
  const float* W      = (const float*)d_in[2];
  const float* b      = (const float*)d_in[3];
  const float* gamma  = (const float*)d_in[4];
  const float* beta_ln= (const float*)d_in[5];
  const float* noise  = (const float*)d_in[6];
  const float* sem    = (const float*)d_in[7];

  float4* table = (float4*)d_ws;                 // 96*512*16B = 768 KB
  __bf16* Bf    = (__bf16*)(table + 96 * 512);   // 512*512*2B = 512 KB

  setup_kernel<<<224, 256, 0, stream>>>(W, table, Bf);
  fused_kernel<<<N_TOK / 32, 512, 0, stream>>>(char_idx, pos, table, Bf, b,
                                               gamma, beta_ln, noise, sem,
                                               (float4*)d_out);
}